// Round 12
// baseline (83.036 us; speedup 1.0000x reference)
//
#include <hip/hip_runtime.h>
#include <hip/hip_bf16.h>

#define D 512
#define BM 256
#define BK 64
#define NT 32                 // 8192 / 256
#define NBLK (NT*(NT+1)/2)    // 528 triangular blocks (528 = 8*66)
#define XCHUNK (NBLK/8)       // 66 blocks per XCD chunk

typedef __attribute__((ext_vector_type(8))) short bf16x8;
typedef __attribute__((ext_vector_type(4))) float f32x4;

__device__ inline unsigned short f2bf(float x) {
    __hip_bfloat16 h = __float2bfloat16(x);
    return __builtin_bit_cast(unsigned short, h);
}

// async global -> LDS, 16B per lane; LDS dest is wave-uniform base + lane*16
__device__ inline void gload16(const unsigned short* g, unsigned short* l) {
    __builtin_amdgcn_global_load_lds(
        (const __attribute__((address_space(1))) unsigned int*)g,
        (__attribute__((address_space(3))) unsigned int*)l,
        16, 0, 0);
}

// Kernel A: row L2-norms, normalized bf16 Yn[2N][D], pos[i]=exp(2*cos), zero neg
__global__ __launch_bounds__(128) void prep_kernel(const float* __restrict__ y,
                                                   const float* __restrict__ yh,
                                                   unsigned short* __restrict__ Yn,
                                                   float* __restrict__ pos,
                                                   float* __restrict__ neg, int N) {
    const int i = blockIdx.x;
    const int t = threadIdx.x;
    if (t < 2) neg[2 * i + t] = 0.f;   // fused memset of neg[2N]
    const float4 a = ((const float4*)(y + (size_t)i * D))[t];
    const float4 b = ((const float4*)(yh + (size_t)i * D))[t];
    float sy = a.x*a.x + a.y*a.y + a.z*a.z + a.w*a.w;
    float sh = b.x*b.x + b.y*b.y + b.z*b.z + b.w*b.w;
    float sd = a.x*b.x + a.y*b.y + a.z*b.z + a.w*b.w;
    #pragma unroll
    for (int o = 32; o > 0; o >>= 1) {
        sy += __shfl_xor(sy, o);
        sh += __shfl_xor(sh, o);
        sd += __shfl_xor(sd, o);
    }
    __shared__ float red[3][2];
    const int wv = t >> 6;
    if ((t & 63) == 0) { red[0][wv] = sy; red[1][wv] = sh; red[2][wv] = sd; }
    __syncthreads();
    sy = red[0][0] + red[0][1];
    sh = red[1][0] + red[1][1];
    sd = red[2][0] + red[2][1];
    const float ny = sqrtf(sy), nh = sqrtf(sh);
    const float ry = 1.f / fmaxf(ny, 1e-12f), rh = 1.f / fmaxf(nh, 1e-12f);
    ushort4 oa, ob;
    oa.x = f2bf(a.x * ry); oa.y = f2bf(a.y * ry); oa.z = f2bf(a.z * ry); oa.w = f2bf(a.w * ry);
    ob.x = f2bf(b.x * rh); ob.y = f2bf(b.y * rh); ob.z = f2bf(b.z * rh); ob.w = f2bf(b.w * rh);
    ((ushort4*)(Yn + (size_t)i * D))[t] = oa;
    ((ushort4*)(Yn + (size_t)(i + N) * D))[t] = ob;
    if (t == 0) {
        const float cs = sd / (fmaxf(ny, 1e-8f) * fmaxf(nh, 1e-8f));
        pos[i] = __expf(2.f * cs);
    }
}

// Kernel B: 256x256 tile, 8 waves, 4 phases/K-tile with raw s_barrier.
// DEEP PREFETCH: all 8 quarter-loads of tile kt+1 are issued at the TOP of
// tile kt's body (region-safe: buf[cur^1] fully read two barriers earlier);
// single vmcnt(8) per K-tile completes tile kt (its loads are 4+ phases old)
// while keeping tile kt+1's 8 loads in flight across the barrier. Phases
// contain only ds_read + MFMA. ds_read balance 8/8/4/4 (b1 pre-read at P2).
__global__ __launch_bounds__(512, 2) void simgemm_kernel(const unsigned short* __restrict__ Yn,
                                                         float* __restrict__ neg) {
    const int t0 = blockIdx.x;
    const int t = (t0 & 7) * XCHUNK + (t0 >> 3);
    int bx = (int)((sqrtf(8.f * (float)t + 1.f) - 1.f) * 0.5f);
    while ((bx + 1) * (bx + 2) / 2 <= t) ++bx;
    while (bx * (bx + 1) / 2 > t) --bx;
    const int by = t - bx * (bx + 1) / 2;

    __shared__ unsigned short As[2][BM * BK];   // 2 x 32 KB
    __shared__ unsigned short Bs[2][BM * BK];   // 2 x 32 KB
    const int tid = threadIdx.x;
    const int lane = tid & 63;
    const int w = tid >> 6;                     // 0..7
    const int wm = (w >> 2) * 128;              // 0 / 128
    const int wn = (w & 3) * 64;                // 0 / 64 / 128 / 192
    const int fr = lane & 15;
    const int fq = lane >> 4;
    const int rowA0 = by * BM, rowB0 = bx * BM;

    f32x4 acc[8][4] = {};

    const int srow = tid >> 3;                                  // 0..63
    const int scol = (((tid & 7) ^ ((tid >> 3) & 7)) << 3);     // pre-swizzled source col
    const int ldsoff = w * 512;                                 // wave-uniform elems

    const unsigned short* gA = Yn + (size_t)(rowA0 + srow) * D + scol;
    const unsigned short* gB = Yn + (size_t)(rowB0 + srow) * D + scol;

    auto SQA = [&](int buf, int k0, int q) {
        gload16(gA + (size_t)q * 64 * D + k0, &As[buf][q * 4096 + ldsoff]);
    };
    auto SQB = [&](int buf, int k0, int q) {
        gload16(gB + (size_t)q * 64 * D + k0, &Bs[buf][q * 4096 + ldsoff]);
    };
    auto ldA = [&](bf16x8* dst, int cur, int rbase, int kk) {
        #pragma unroll
        for (int m = 0; m < 4; ++m) {
            const int row = rbase + m * 16 + fr;
            const int koff = ((((kk >> 3) + fq) ^ (row & 7)) << 3);
            dst[m] = *(bf16x8*)&As[cur][row * BK + koff];
        }
    };
    auto ldB = [&](bf16x8* dst, int cur, int kk) {
        #pragma unroll
        for (int n = 0; n < 4; ++n) {
            const int row = wn + n * 16 + fr;
            const int koff = ((((kk >> 3) + fq) ^ (row & 7)) << 3);
            dst[n] = *(bf16x8*)&Bs[cur][row * BK + koff];
        }
    };

    // prologue: tile 0 into buf0 (no wait here; first loop iter waits)
    #pragma unroll
    for (int q = 0; q < 4; ++q) { SQA(0, 0, q); SQB(0, 0, q); }

    for (int kt = 0; kt < 7; ++kt) {
        const int cur = kt & 1;
        const int k1 = (kt + 1) * BK;
        // top: issue ALL of tile kt+1 into buf[cur^1] (read by t kt-1 is long done)
        #pragma unroll
        for (int q = 0; q < 4; ++q) { SQA(cur ^ 1, k1, q); SQB(cur ^ 1, k1, q); }
        asm volatile("s_waitcnt vmcnt(8)" ::: "memory");   // tile kt landed; kt+1 in flight
        __builtin_amdgcn_s_barrier();

        bf16x8 af[4], ag[4], b0[4], b1[4];
        // ---- P1: (kk0, mlo)
        ldA(af, cur, wm, 0);
        ldB(b0, cur, 0);
        __builtin_amdgcn_s_barrier();
        asm volatile("s_waitcnt lgkmcnt(0)" ::: "memory");
        __builtin_amdgcn_s_setprio(1);
        #pragma unroll
        for (int m = 0; m < 4; ++m)
            #pragma unroll
            for (int n = 0; n < 4; ++n)
                acc[m][n] = __builtin_amdgcn_mfma_f32_16x16x32_bf16(af[m], b0[n], acc[m][n], 0, 0, 0);
        __builtin_amdgcn_s_setprio(0);
        __builtin_amdgcn_s_barrier();
        // ---- P2: (kk0, mhi) + pre-read b1
        ldA(ag, cur, wm + 64, 0);
        ldB(b1, cur, 32);
        __builtin_amdgcn_s_barrier();
        asm volatile("s_waitcnt lgkmcnt(0)" ::: "memory");
        __builtin_amdgcn_s_setprio(1);
        #pragma unroll
        for (int m = 0; m < 4; ++m)
            #pragma unroll
            for (int n = 0; n < 4; ++n)
                acc[m + 4][n] = __builtin_amdgcn_mfma_f32_16x16x32_bf16(ag[m], b0[n], acc[m + 4][n], 0, 0, 0);
        __builtin_amdgcn_s_setprio(0);
        __builtin_amdgcn_s_barrier();
        // ---- P3: (kk1, mlo)
        ldA(af, cur, wm, 32);
        __builtin_amdgcn_s_barrier();
        asm volatile("s_waitcnt lgkmcnt(0)" ::: "memory");
        __builtin_amdgcn_s_setprio(1);
        #pragma unroll
        for (int m = 0; m < 4; ++m)
            #pragma unroll
            for (int n = 0; n < 4; ++n)
                acc[m][n] = __builtin_amdgcn_mfma_f32_16x16x32_bf16(af[m], b1[n], acc[m][n], 0, 0, 0);
        __builtin_amdgcn_s_setprio(0);
        __builtin_amdgcn_s_barrier();
        // ---- P4: (kk1, mhi)
        ldA(ag, cur, wm + 64, 32);
        __builtin_amdgcn_s_barrier();
        asm volatile("s_waitcnt lgkmcnt(0)" ::: "memory");
        __builtin_amdgcn_s_setprio(1);
        #pragma unroll
        for (int m = 0; m < 4; ++m)
            #pragma unroll
            for (int n = 0; n < 4; ++n)
                acc[m + 4][n] = __builtin_amdgcn_mfma_f32_16x16x32_bf16(ag[m], b1[n], acc[m + 4][n], 0, 0, 0);
        __builtin_amdgcn_s_setprio(0);
        __builtin_amdgcn_s_barrier();
    }
    // ---- epilogue: tile 7 in buf[1] (issued at kt=6 top, 4+ phases old)
    asm volatile("s_waitcnt vmcnt(0)" ::: "memory");
    __builtin_amdgcn_s_barrier();
    {
        #pragma unroll
        for (int kk = 0; kk < BK; kk += 32) {
            bf16x8 af[4], ag[4], bb[4];
            ldA(af, 1, wm, kk);
            ldA(ag, 1, wm + 64, kk);
            ldB(bb, 1, kk);
            #pragma unroll
            for (int m = 0; m < 4; ++m)
                #pragma unroll
                for (int n = 0; n < 4; ++n) {
                    acc[m][n]     = __builtin_amdgcn_mfma_f32_16x16x32_bf16(af[m], bb[n], acc[m][n], 0, 0, 0);
                    acc[m + 4][n] = __builtin_amdgcn_mfma_f32_16x16x32_bf16(ag[m], bb[n], acc[m + 4][n], 0, 0, 0);
                }
        }
    }

    const bool diagblk = (bx == by);
    #pragma unroll
    for (int m = 0; m < 8; ++m)
        #pragma unroll
        for (int n = 0; n < 4; ++n)
            #pragma unroll
            for (int r = 0; r < 4; ++r) {
                const float e = __expf(2.f * acc[m][n][r]);
                const bool diag = diagblk && (wm + m * 16 + fq * 4 + r) == (wn + n * 16 + fr);
                acc[m][n][r] = diag ? 0.f : e;
            }
    #pragma unroll
    for (int m = 0; m < 8; ++m)
        #pragma unroll
        for (int r = 0; r < 4; ++r) {
            float v = acc[m][0][r] + acc[m][1][r] + acc[m][2][r] + acc[m][3][r];
            v += __shfl_xor(v, 1);
            v += __shfl_xor(v, 2);
            v += __shfl_xor(v, 4);
            v += __shfl_xor(v, 8);
            if (fr == 0) atomicAdd(&neg[rowA0 + wm + m * 16 + fq * 4 + r], v);
        }
    if (!diagblk) {
        #pragma unroll
        for (int n = 0; n < 4; ++n) {
            float v = 0.f;
            #pragma unroll
            for (int m = 0; m < 8; ++m)
                #pragma unroll
                for (int r = 0; r < 4; ++r) v += acc[m][n][r];
            v += __shfl_xor(v, 16);
            v += __shfl_xor(v, 32);
            if (fq == 0) atomicAdd(&neg[rowB0 + wn + n * 16 + fr], v);
        }
    }
}

// Kernel C: loss = log(2N) - log( sum_i pos[i] * (1/neg[i] + 1/neg[i+N]) )
__global__ __launch_bounds__(1024) void finish_kernel(const float* __restrict__ pos,
                                                      const float* __restrict__ neg,
                                                      float* __restrict__ out, int N) {
    float s = 0.f;
    for (int i = threadIdx.x; i < N; i += 1024)
        s += pos[i] * (1.f / neg[i] + 1.f / neg[i + N]);
    #pragma unroll
    for (int o = 32; o > 0; o >>= 1) s += __shfl_xor(s, o);
    __shared__ float red[16];
    const int wv = threadIdx.x >> 6;
    if ((threadIdx.x & 63) == 0) red[wv] = s;
    __syncthreads();
    if (threadIdx.x == 0) {
        float tot = 0.f;
        #pragma unroll
        for (int k = 0; k < 16; ++k) tot += red[k];
        out[0] = logf(2.f * (float)N) - logf(tot);
    }
}

extern "C" void kernel_launch(void* const* d_in, const int* in_sizes, int n_in,
                              void* d_out, int out_size, void* d_ws, size_t ws_size,
                              hipStream_t stream) {
    const float* y  = (const float*)d_in[0];
    const float* yh = (const float*)d_in[1];
    const int N  = in_sizes[0] / D;   // 4096
    const int N2 = 2 * N;             // 8192

    unsigned short* Yn = (unsigned short*)d_ws;                 // [2N][D] bf16, 8 MB
    const size_t yn_bytes = (size_t)N2 * D * sizeof(unsigned short);
    float* neg = (float*)((char*)d_ws + yn_bytes);              // [2N]
    float* pos = neg + N2;                                      // [N]
    float* out = (float*)d_out;

    prep_kernel<<<N, 128, 0, stream>>>(y, yh, Yn, pos, neg, N);
    simgemm_kernel<<<NBLK, 512, 0, stream>>>(Yn, neg);
    finish_kernel<<<1, 1024, 0, stream>>>(pos, neg, out, N);
}

// Round 14
// 78.069 us; speedup vs baseline: 1.0636x; 1.0636x over previous
//
#include <hip/hip_runtime.h>
#include <hip/hip_bf16.h>

#define D 512
#define BM 256
#define BK 64
#define NT 32                 // 8192 / 256
#define NBLK (NT*(NT+1)/2)    // 528 triangular blocks (528 = 8*66)
#define XCHUNK (NBLK/8)       // 66 blocks per XCD chunk
#define N2ROWS 8192

typedef __attribute__((ext_vector_type(8))) short bf16x8;
typedef __attribute__((ext_vector_type(4))) float f32x4;

__device__ inline unsigned short f2bf(float x) {
    __hip_bfloat16 h = __float2bfloat16(x);
    return __builtin_bit_cast(unsigned short, h);
}

// async global -> LDS, 16B per lane; LDS dest is wave-uniform base + lane*16
__device__ inline void gload16(const unsigned short* g, unsigned short* l) {
    __builtin_amdgcn_global_load_lds(
        (const __attribute__((address_space(1))) unsigned int*)g,
        (__attribute__((address_space(3))) unsigned int*)l,
        16, 0, 0);
}

// Kernel A: row L2-norms, normalized bf16 Yn[2N][D], pos[i]=exp(2*cos); zero total
__global__ __launch_bounds__(128) void prep_kernel(const float* __restrict__ y,
                                                   const float* __restrict__ yh,
                                                   unsigned short* __restrict__ Yn,
                                                   float* __restrict__ pos,
                                                   float* __restrict__ total, int N) {
    const int i = blockIdx.x;
    const int t = threadIdx.x;
    if (i == 0 && t == 1) total[0] = 0.f;
    const float4 a = ((const float4*)(y + (size_t)i * D))[t];
    const float4 b = ((const float4*)(yh + (size_t)i * D))[t];
    float sy = a.x*a.x + a.y*a.y + a.z*a.z + a.w*a.w;
    float sh = b.x*b.x + b.y*b.y + b.z*b.z + b.w*b.w;
    float sd = a.x*b.x + a.y*b.y + a.z*b.z + a.w*b.w;
    #pragma unroll
    for (int o = 32; o > 0; o >>= 1) {
        sy += __shfl_xor(sy, o);
        sh += __shfl_xor(sh, o);
        sd += __shfl_xor(sd, o);
    }
    __shared__ float red[3][2];
    const int wv = t >> 6;
    if ((t & 63) == 0) { red[0][wv] = sy; red[1][wv] = sh; red[2][wv] = sd; }
    __syncthreads();
    sy = red[0][0] + red[0][1];
    sh = red[1][0] + red[1][1];
    sd = red[2][0] + red[2][1];
    const float ny = sqrtf(sy), nh = sqrtf(sh);
    const float ry = 1.f / fmaxf(ny, 1e-12f), rh = 1.f / fmaxf(nh, 1e-12f);
    ushort4 oa, ob;
    oa.x = f2bf(a.x * ry); oa.y = f2bf(a.y * ry); oa.z = f2bf(a.z * ry); oa.w = f2bf(a.w * ry);
    ob.x = f2bf(b.x * rh); ob.y = f2bf(b.y * rh); ob.z = f2bf(b.z * rh); ob.w = f2bf(b.w * rh);
    ((ushort4*)(Yn + (size_t)i * D))[t] = oa;
    ((ushort4*)(Yn + (size_t)(i + N) * D))[t] = ob;
    if (t == 0) {
        const float cs = sd / (fmaxf(ny, 1e-8f) * fmaxf(nh, 1e-8f));
        pos[i] = __expf(2.f * cs);
    }
}

// Kernel B: R11 GEMM core (counted vmcnt, 4 phases/K-tile). Epilogue: per-wave
// partials -> LDS (redR[row][wn-quad], redC[col][wm-half], each slot single-
// writer) -> __syncthreads -> combined sums stored to slab (no global atomics).
// slab[q][i] = contribution of column-panel q to neg[i]; written exactly once:
//   q>=p by block (q,p) row-side; q<p by block (p,q) col-side (diag: row only).
__global__ __launch_bounds__(512, 2) void simgemm_kernel(const unsigned short* __restrict__ Yn,
                                                         float* __restrict__ slab) {
    const int t0 = blockIdx.x;
    const int t = (t0 & 7) * XCHUNK + (t0 >> 3);
    int bx = (int)((sqrtf(8.f * (float)t + 1.f) - 1.f) * 0.5f);
    while ((bx + 1) * (bx + 2) / 2 <= t) ++bx;
    while (bx * (bx + 1) / 2 > t) --bx;
    const int by = t - bx * (bx + 1) / 2;

    __shared__ unsigned short As[2][BM * BK];
    __shared__ unsigned short Bs[2][BM * BK];
    __shared__ float redR[256][4];   // row partials per wn-quadrant
    __shared__ float redC[256][2];   // col partials per wm-half
    const int tid = threadIdx.x;
    const int lane = tid & 63;
    const int w = tid >> 6;
    const int wm = (w >> 2) * 128;
    const int wn = (w & 3) * 64;
    const int fr = lane & 15;
    const int fq = lane >> 4;
    const int rowA0 = by * BM, rowB0 = bx * BM;

    f32x4 acc[8][4] = {};

    const int srow = tid >> 3;
    const int scol = (((tid & 7) ^ ((tid >> 3) & 7)) << 3);
    const int ldsoff = w * 512;

    const unsigned short* gA = Yn + (size_t)(rowA0 + srow) * D + scol;
    const unsigned short* gB = Yn + (size_t)(rowB0 + srow) * D + scol;

    auto SQA = [&](int buf, int k0, int q) {
        gload16(gA + (size_t)q * 64 * D + k0, &As[buf][q * 4096 + ldsoff]);
    };
    auto SQB = [&](int buf, int k0, int q) {
        gload16(gB + (size_t)q * 64 * D + k0, &Bs[buf][q * 4096 + ldsoff]);
    };
    auto ldA = [&](bf16x8* dst, int cur, int rbase, int kk) {
        #pragma unroll
        for (int m = 0; m < 4; ++m) {
            const int row = rbase + m * 16 + fr;
            const int koff = ((((kk >> 3) + fq) ^ (row & 7)) << 3);
            dst[m] = *(bf16x8*)&As[cur][row * BK + koff];
        }
    };
    auto ldB = [&](bf16x8* dst, int cur, int kk) {
        #pragma unroll
        for (int n = 0; n < 4; ++n) {
            const int row = wn + n * 16 + fr;
            const int koff = ((((kk >> 3) + fq) ^ (row & 7)) << 3);
            dst[n] = *(bf16x8*)&Bs[cur][row * BK + koff];
        }
    };

    // prologue: tile0 + tile1 A-q0,q2 -> 10 in flight, keep 2
    #pragma unroll
    for (int q = 0; q < 4; ++q) { SQA(0, 0, q); SQB(0, 0, q); }
    SQA(1, BK, 0); SQA(1, BK, 2);
    asm volatile("s_waitcnt vmcnt(2)" ::: "memory");
    __builtin_amdgcn_s_barrier();

    for (int kt = 0; kt < 7; ++kt) {
        const int cur = kt & 1, nxt = cur ^ 1;
        const int k1 = (kt + 1) * BK;
        bf16x8 af[4], ag[4], b0[4], b1[4];
        // ---- P1: (kk0, mlo)
        ldA(af, cur, wm, 0);
        ldB(b0, cur, 0);
        SQA(nxt, k1, 1); SQA(nxt, k1, 3);
        __builtin_amdgcn_s_barrier();
        asm volatile("s_waitcnt lgkmcnt(0)" ::: "memory");
        __builtin_amdgcn_s_setprio(1);
        #pragma unroll
        for (int m = 0; m < 4; ++m)
            #pragma unroll
            for (int n = 0; n < 4; ++n)
                acc[m][n] = __builtin_amdgcn_mfma_f32_16x16x32_bf16(af[m], b0[n], acc[m][n], 0, 0, 0);
        __builtin_amdgcn_s_setprio(0);
        __builtin_amdgcn_s_barrier();
        // ---- P2: (kk0, mhi)
        ldA(ag, cur, wm + 64, 0);
        SQB(nxt, k1, 0); SQB(nxt, k1, 1);
        __builtin_amdgcn_s_barrier();
        asm volatile("s_waitcnt lgkmcnt(0)" ::: "memory");
        __builtin_amdgcn_s_setprio(1);
        #pragma unroll
        for (int m = 0; m < 4; ++m)
            #pragma unroll
            for (int n = 0; n < 4; ++n)
                acc[m + 4][n] = __builtin_amdgcn_mfma_f32_16x16x32_bf16(ag[m], b0[n], acc[m + 4][n], 0, 0, 0);
        __builtin_amdgcn_s_setprio(0);
        __builtin_amdgcn_s_barrier();
        // ---- P3: (kk1, mlo)
        ldA(af, cur, wm, 32);
        ldB(b1, cur, 32);
        SQB(nxt, k1, 2); SQB(nxt, k1, 3);
        __builtin_amdgcn_s_barrier();
        asm volatile("s_waitcnt lgkmcnt(0)" ::: "memory");
        __builtin_amdgcn_s_setprio(1);
        #pragma unroll
        for (int m = 0; m < 4; ++m)
            #pragma unroll
            for (int n = 0; n < 4; ++n)
                acc[m][n] = __builtin_amdgcn_mfma_f32_16x16x32_bf16(af[m], b1[n], acc[m][n], 0, 0, 0);
        __builtin_amdgcn_s_setprio(0);
        __builtin_amdgcn_s_barrier();
        // ---- P4: (kk1, mhi)
        ldA(ag, cur, wm + 64, 32);
        if (kt < 6) { SQA(cur, k1 + BK, 0); SQA(cur, k1 + BK, 2); }
        __builtin_amdgcn_s_barrier();
        asm volatile("s_waitcnt lgkmcnt(0)" ::: "memory");
        __builtin_amdgcn_s_setprio(1);
        #pragma unroll
        for (int m = 0; m < 4; ++m)
            #pragma unroll
            for (int n = 0; n < 4; ++n)
                acc[m + 4][n] = __builtin_amdgcn_mfma_f32_16x16x32_bf16(ag[m], b1[n], acc[m + 4][n], 0, 0, 0);
        __builtin_amdgcn_s_setprio(0);
        if (kt < 6) asm volatile("s_waitcnt vmcnt(2)" ::: "memory");
        else        asm volatile("s_waitcnt vmcnt(0)" ::: "memory");
        __builtin_amdgcn_s_barrier();
    }
    // ---- epilogue K-tile 7 (buf 1, fully resident)
    {
        #pragma unroll
        for (int kk = 0; kk < BK; kk += 32) {
            bf16x8 af[4], ag[4], bb[4];
            ldA(af, 1, wm, kk);
            ldA(ag, 1, wm + 64, kk);
            ldB(bb, 1, kk);
            #pragma unroll
            for (int m = 0; m < 4; ++m)
                #pragma unroll
                for (int n = 0; n < 4; ++n) {
                    acc[m][n]     = __builtin_amdgcn_mfma_f32_16x16x32_bf16(af[m], bb[n], acc[m][n], 0, 0, 0);
                    acc[m + 4][n] = __builtin_amdgcn_mfma_f32_16x16x32_bf16(ag[m], bb[n], acc[m + 4][n], 0, 0, 0);
                }
        }
    }

    const bool diagblk = (bx == by);
    #pragma unroll
    for (int m = 0; m < 8; ++m)
        #pragma unroll
        for (int n = 0; n < 4; ++n)
            #pragma unroll
            for (int r = 0; r < 4; ++r) {
                const float e = __expf(2.f * acc[m][n][r]);
                const bool diag = diagblk && (wm + m * 16 + fq * 4 + r) == (wn + n * 16 + fr);
                acc[m][n][r] = diag ? 0.f : e;
            }
    // per-wave ROW partials (sum over this wave's 64 cols) -> redR[row][wn-quad]
    #pragma unroll
    for (int m = 0; m < 8; ++m)
        #pragma unroll
        for (int r = 0; r < 4; ++r) {
            float v = acc[m][0][r] + acc[m][1][r] + acc[m][2][r] + acc[m][3][r];
            v += __shfl_xor(v, 1);
            v += __shfl_xor(v, 2);
            v += __shfl_xor(v, 4);
            v += __shfl_xor(v, 8);
            if (fr == 0) redR[wm + m * 16 + fq * 4 + r][w & 3] = v;
        }
    // per-wave COL partials (sum over this wave's 128 rows) -> redC[col][wm-half]
    if (!diagblk) {
        #pragma unroll
        for (int n = 0; n < 4; ++n) {
            float v = 0.f;
            #pragma unroll
            for (int m = 0; m < 8; ++m)
                #pragma unroll
                for (int r = 0; r < 4; ++r) v += acc[m][n][r];
            v += __shfl_xor(v, 16);
            v += __shfl_xor(v, 32);
            if (fq == 0) redC[wn + n * 16 + fr][w >> 2] = v;
        }
    }
    __syncthreads();
    // combine across waves; single store per slab slot
    if (tid < 256) {
        const float v = redR[tid][0] + redR[tid][1] + redR[tid][2] + redR[tid][3];
        slab[(size_t)bx * N2ROWS + rowA0 + tid] = v;
    } else if (!diagblk) {
        const int c = tid - 256;
        const float v = redC[c][0] + redC[c][1];
        slab[(size_t)by * N2ROWS + rowB0 + c] = v;
    }
}

// Kernel C1: per-row neg = sum of 32 partials; s = pos/neg; block-reduce; 32 atomics
__global__ __launch_bounds__(256) void reduce_kernel(const float* __restrict__ slab,
                                                     const float* __restrict__ pos,
                                                     float* __restrict__ total, int N) {
    const int i = blockIdx.x * 256 + threadIdx.x;   // 0..8191
    float neg = 0.f;
    #pragma unroll
    for (int q = 0; q < NT; ++q) neg += slab[(size_t)q * N2ROWS + i];
    const float p = pos[i < N ? i : i - N];
    float s = p / neg;
    #pragma unroll
    for (int o = 32; o > 0; o >>= 1) s += __shfl_xor(s, o);
    __shared__ float red[4];
    if ((threadIdx.x & 63) == 0) red[threadIdx.x >> 6] = s;
    __syncthreads();
    if (threadIdx.x == 0) atomicAdd(total, red[0] + red[1] + red[2] + red[3]);
}

// Kernel C2: loss = log(2N) - log(total)
__global__ void final_kernel(const float* __restrict__ total,
                             float* __restrict__ out, int N) {
    out[0] = logf(2.f * (float)N) - logf(total[0]);
}

extern "C" void kernel_launch(void* const* d_in, const int* in_sizes, int n_in,
                              void* d_out, int out_size, void* d_ws, size_t ws_size,
                              hipStream_t stream) {
    const float* y  = (const float*)d_in[0];
    const float* yh = (const float*)d_in[1];
    const int N  = in_sizes[0] / D;   // 4096
    const int N2 = 2 * N;             // 8192

    unsigned short* Yn = (unsigned short*)d_ws;                  // [2N][D] bf16, 8 MB
    const size_t yn_bytes = (size_t)N2 * D * sizeof(unsigned short);
    float* slab  = (float*)((char*)d_ws + yn_bytes);             // [32][8192] = 1 MB
    float* pos   = slab + (size_t)NT * N2ROWS;                   // [N]
    float* total = pos + N;                                      // [1]
    float* out = (float*)d_out;

    prep_kernel<<<N, 128, 0, stream>>>(y, yh, Yn, pos, total, N);
    simgemm_kernel<<<NBLK, 512, 0, stream>>>(Yn, slab);
    reduce_kernel<<<N2 / 256, 256, 0, stream>>>(slab, pos, total, N);
    final_kernel<<<1, 1, 0, stream>>>(total, out, N);
}